// Round 9
// baseline (282.111 us; speedup 1.0000x reference)
//
#include <hip/hip_runtime.h>

// C3 partial conv: x[64,6,256,256] f32, W[16,6,5,5] f32 (sparse table), b[16].
// out[64,16,252,252] f32 = 1.7159*tanh((2/3)*(conv_valid + b)).
//
// Round 12: packed math via LAYOUT, not packing ops. Plateau r5/r7/r9/r11 =
// 275-296us across 43-82% occupancy -> wall is per-wave VALU stream length
// (~6-7.6K instrs/thread vs 3000-FMA floor; r11's kx-packing ADDED instrs via
// mk2 packs + horizontal folds). Fix: pack the TWO OUTPUT ROWS as the packed
// lanes. LDS tile stored pre-paired: ldsP[c][pr][col] = (row pr, row pr+1)
// (pairs built during staging when values are already in regs). Window tap =
// one aligned ds_read_b64 (25/c vs r7's 30 b32). Weights pre-DUPLICATED
// (w,w) in d_ws (prep kernel) -> stay on scalar path (r10 lesson), s_load
// pairs feed v_pk_fma_f32 directly via __builtin_elementwise_fma (LLVM
// selects pk from llvm.fma.v2f32 on gfx90a+). Per (o,c): 25 pk_fma + 1
// pk_add, no packing, no folds. Two alternating temps break the acc chain.
// Worst case (scalarized): = r7's 50 FMA, bounded downside.
// NO launch_bounds min-waves arg (hard VGPR clamp -> scratch, r2/r4).

typedef float v2f __attribute__((ext_vector_type(2)));

__global__ void prep_weights(const float* __restrict__ W, float* __restrict__ Wp) {
    int i = blockIdx.x * 256 + threadIdx.x;   // 0..6143
    if (i < 96 * 64) {
        int oc = i >> 6, k = i & 63;
        Wp[i] = (k < 50) ? W[oc * 25 + (k >> 1)] : 0.0f;   // (w,w) duplicated pairs
    }
}

// acc.x += sum w*win_row0 ; acc.y += sum w*win_row1  -- 25 pk_fma + 1 pk_add
__device__ __forceinline__ void convpk(const v2f* __restrict__ w2,
                                       const v2f (&win)[5][5], v2f& acc) {
    v2f t0 = acc;
    v2f t1 = {0.0f, 0.0f};
    #pragma unroll
    for (int ky = 0; ky < 5; ++ky)
        #pragma unroll
        for (int kx = 0; kx < 5; ++kx) {
            if (ky & 1) t1 = __builtin_elementwise_fma(win[ky][kx], w2[ky * 5 + kx], t1);
            else        t0 = __builtin_elementwise_fma(win[ky][kx], w2[ky * 5 + kx], t0);
        }
    acc = t0 + t1;
}

__global__ __launch_bounds__(256) void c3_partial_conv_kernel(
    const float* __restrict__ x,    // [64,6,256,256]
    const float* __restrict__ Wp,   // [96][64] duplicated-pair weights (d_ws)
    const float* __restrict__ b,    // [16]
    float* __restrict__ out)        // [64,16,252,252]
{
    constexpr int G0N[6] = {4, 5, 5, 5, 4, 3};
    constexpr int G0O[6][5] = {
        {0, 4, 5, 6, 0},
        {0, 1, 5, 6, 7},
        {0, 1, 2, 6, 7},
        {1, 2, 3, 6, 7},
        {2, 3, 4, 7, 0},
        {3, 4, 5, 0, 0}};
    constexpr int G1N[6] = {6, 5, 5, 5, 6, 7};
    constexpr int G1O[6][7] = {
        {9, 10, 11, 12, 14, 15, 8},
        {10, 11, 12, 13, 15, 8, 8},
        {8, 11, 13, 14, 15, 8, 8},
        {8, 9, 12, 14, 15, 8, 8},
        {8, 9, 10, 12, 13, 15, 8},
        {8, 9, 10, 11, 13, 14, 15}};

    // Vertically-paired tile: ldsP[c][pr][col] = (row pr, row pr+1).
    __shared__ v2f ldsP[6][19][40];   // 36480 B -> 4 blocks/CU

    const int tx  = threadIdx.x;
    const int ty  = threadIdx.y;
    const int tid = ty * 32 + tx;

    const int tileX = blockIdx.x << 5;   // 0..224
    const int tileY = blockIdx.y << 4;   // 0..240
    const int batch = blockIdx.z;

    const float* xb = x + (size_t)batch * 6 * 256 * 256;

    // ---- stage: 6 ch x 19 pair-rows x 9 float4-chunks = 1026 ----
    for (int i = tid; i < 1026; i += 256) {
        int c   = i / 171;            // 19*9
        int rem = i - c * 171;
        int pr  = rem / 9;
        int q   = rem - pr * 9;
        int gr  = tileY + pr;
        int gc0 = tileX + (q << 2);
        float4 a = make_float4(0.f, 0.f, 0.f, 0.f);
        float4 d = make_float4(0.f, 0.f, 0.f, 0.f);
        if (gc0 < 256) {
            const float* rowp = &xb[(c * 256 + gr) * 256 + gc0];
            if (gr < 256)     a = *reinterpret_cast<const float4*>(rowp);
            if (gr + 1 < 256) d = *reinterpret_cast<const float4*>(rowp + 256);
        }
        v2f* dst = &ldsP[c][pr][q << 2];
        dst[0] = v2f{a.x, d.x};
        dst[1] = v2f{a.y, d.y};
        dst[2] = v2f{a.z, d.z};
        dst[3] = v2f{a.w, d.w};
    }
    __syncthreads();

    const int row0 = ty << 1;            // 0..14
    const int ocol = tileX + tx;
    float* ob = out + (size_t)batch * 16 * 252 * 252;
    const bool colok = (ocol < 252);
    const v2f* w2base = reinterpret_cast<const v2f*>(Wp);

    // ================= group 0 : out 0..7 =================
    {
        v2f accp[8];
        #pragma unroll
        for (int o = 0; o < 8; ++o) { float bv = b[o]; accp[o] = v2f{bv, bv}; }

        #pragma unroll 1
        for (int c = 0; c < 6; ++c) {
            v2f win[5][5];
            const v2f* cb = &ldsP[c][row0][tx];
            #pragma unroll
            for (int ky = 0; ky < 5; ++ky)
                #pragma unroll
                for (int kx = 0; kx < 5; ++kx)
                    win[ky][kx] = cb[ky * 40 + kx];   // aligned ds_read_b64

            const int n = G0N[c];
            #pragma unroll 1
            for (int oi = 0; oi < n; ++oi) {
                const int o = G0O[c][oi];
                switch (o) {                   // routes accumulator only
                    case 0: convpk(w2base + (0 * 6 + c) * 32, win, accp[0]); break;
                    case 1: convpk(w2base + (1 * 6 + c) * 32, win, accp[1]); break;
                    case 2: convpk(w2base + (2 * 6 + c) * 32, win, accp[2]); break;
                    case 3: convpk(w2base + (3 * 6 + c) * 32, win, accp[3]); break;
                    case 4: convpk(w2base + (4 * 6 + c) * 32, win, accp[4]); break;
                    case 5: convpk(w2base + (5 * 6 + c) * 32, win, accp[5]); break;
                    case 6: convpk(w2base + (6 * 6 + c) * 32, win, accp[6]); break;
                    case 7: convpk(w2base + (7 * 6 + c) * 32, win, accp[7]); break;
                    default: break;
                }
            }
        }

        if (colok) {
            #pragma unroll
            for (int o = 0; o < 8; ++o) {
                float av[2] = {accp[o].x, accp[o].y};
                #pragma unroll
                for (int dy = 0; dy < 2; ++dy) {
                    int orow = tileY + row0 + dy;
                    if (orow < 252) {
                        float z = av[dy] * (2.0f / 3.0f);
                        float e = __expf(2.0f * z);
                        float rr = __builtin_amdgcn_rcpf(e + 1.0f);
                        ob[(o * 252 + orow) * 252 + ocol] = 1.7159f * (1.0f - 2.0f * rr);
                    }
                }
            }
        }
    }

    __builtin_amdgcn_sched_barrier(0);

    // ================= group 1 : out 8..15 =================
    {
        v2f accp[8];
        #pragma unroll
        for (int o = 0; o < 8; ++o) { float bv = b[8 + o]; accp[o] = v2f{bv, bv}; }

        #pragma unroll 1
        for (int c = 0; c < 6; ++c) {
            v2f win[5][5];
            const v2f* cb = &ldsP[c][row0][tx];
            #pragma unroll
            for (int ky = 0; ky < 5; ++ky)
                #pragma unroll
                for (int kx = 0; kx < 5; ++kx)
                    win[ky][kx] = cb[ky * 40 + kx];

            const int n = G1N[c];
            #pragma unroll 1
            for (int oi = 0; oi < n; ++oi) {
                const int o = G1O[c][oi];
                switch (o) {
                    case  8: convpk(w2base + ( 8 * 6 + c) * 32, win, accp[0]); break;
                    case  9: convpk(w2base + ( 9 * 6 + c) * 32, win, accp[1]); break;
                    case 10: convpk(w2base + (10 * 6 + c) * 32, win, accp[2]); break;
                    case 11: convpk(w2base + (11 * 6 + c) * 32, win, accp[3]); break;
                    case 12: convpk(w2base + (12 * 6 + c) * 32, win, accp[4]); break;
                    case 13: convpk(w2base + (13 * 6 + c) * 32, win, accp[5]); break;
                    case 14: convpk(w2base + (14 * 6 + c) * 32, win, accp[6]); break;
                    case 15: convpk(w2base + (15 * 6 + c) * 32, win, accp[7]); break;
                    default: break;
                }
            }
        }

        if (colok) {
            #pragma unroll
            for (int o = 0; o < 8; ++o) {
                float av[2] = {accp[o].x, accp[o].y};
                #pragma unroll
                for (int dy = 0; dy < 2; ++dy) {
                    int orow = tileY + row0 + dy;
                    if (orow < 252) {
                        float z = av[dy] * (2.0f / 3.0f);
                        float e = __expf(2.0f * z);
                        float rr = __builtin_amdgcn_rcpf(e + 1.0f);
                        ob[((8 + o) * 252 + orow) * 252 + ocol] = 1.7159f * (1.0f - 2.0f * rr);
                    }
                }
            }
        }
    }
}

extern "C" void kernel_launch(void* const* d_in, const int* in_sizes, int n_in,
                              void* d_out, int out_size, void* d_ws, size_t ws_size,
                              hipStream_t stream) {
    const float* x = (const float*)d_in[0];
    const float* W = (const float*)d_in[1];
    const float* b = (const float*)d_in[2];
    float* out = (float*)d_out;
    float* Wp  = (float*)d_ws;     // needs 96*64*4 = 24576 B

    hipLaunchKernelGGL(prep_weights, dim3(24), dim3(256), 0, stream, W, Wp);

    dim3 grid(8, 16, 64);
    dim3 block(32, 8);
    hipLaunchKernelGGL(c3_partial_conv_kernel, grid, block, 0, stream, x, Wp, b, out);
}